// Round 1
// baseline (2134.320 us; speedup 1.0000x reference)
//
#include <hip/hip_runtime.h>
#include <cfloat>
#include <climits>
#include <cstdint>

#define NPOINTS 32768
#define NBATCH  2
#define NSEG    4
#define KTILE   256
#define NBLK    64

// ---------------- KNN over a voxel segment: per-point top-3 (exact f32 replication) ----------------
__global__ __launch_bounds__(256) void knn_seg_kernel(
    const float* __restrict__ ptc,   // [B, Np, 3]
    const float* __restrict__ voxc,  // [B, Nv, 3]
    int Nv,
    float* __restrict__ cd2,         // [B*Np, NSEG, 3]
    int*   __restrict__ cidx)        // [B*Np, NSEG, 3]
{
  const int b = blockIdx.y, s = blockIdx.z;
  const int p = blockIdx.x * 256 + threadIdx.x;
  const float* pp = ptc + ((size_t)b * NPOINTS + p) * 3;
  const float px = pp[0], py = pp[1], pz = pp[2];

  const int segNv = Nv / NSEG;            // all Nv divisible by NSEG*KTILE
  const int v0 = s * segNv, v1 = v0 + segNv;
  const float* vb = voxc + (size_t)b * Nv * 3;

  __shared__ float sv[KTILE * 4];         // x,y,z,pad per voxel (16B aligned reads)

  float b0 = FLT_MAX, b1 = FLT_MAX, b2 = FLT_MAX;
  int   i0 = 0, i1 = 0, i2 = 0;

  for (int t = v0; t < v1; t += KTILE) {
    const int n = min(KTILE, v1 - t);
    __syncthreads();
    for (int e = threadIdx.x; e < n * 3; e += 256) {
      int j = e / 3, d = e - j * 3;
      sv[j * 4 + d] = vb[(size_t)t * 3 + e];
    }
    __syncthreads();
    #pragma unroll 4
    for (int j = 0; j < n; ++j) {
      // exact reference arithmetic: individually-rounded squares, (x2+y2)+z2
      float dx = px - sv[j * 4 + 0];
      float dy = py - sv[j * 4 + 1];
      float dz = pz - sv[j * 4 + 2];
      float d2 = __fadd_rn(__fadd_rn(__fmul_rn(dx, dx), __fmul_rn(dy, dy)),
                           __fmul_rn(dz, dz));
      if (d2 < b2) {                       // strict <: earlier index wins ties (stable top-k)
        int vi = t + j;
        if (d2 < b1) {
          b2 = b1; i2 = i1;
          if (d2 < b0) { b1 = b0; i1 = i0; b0 = d2; i0 = vi; }
          else         { b1 = d2; i1 = vi; }
        } else { b2 = d2; i2 = vi; }
      }
    }
  }

  size_t base = (((size_t)b * NPOINTS + p) * NSEG + s) * 3;
  cd2[base]     = b0; cd2[base + 1] = b1; cd2[base + 2] = b2;
  cidx[base]    = i0; cidx[base + 1] = i1; cidx[base + 2] = i2;
}

// ---------------- Merge segment candidates lexicographically by (d2, idx), compute weights ----------------
__global__ __launch_bounds__(256) void knn_merge_kernel(
    const float* __restrict__ cd2, const int* __restrict__ cidx,
    int* __restrict__ idxo,          // [B*Np, 3]
    float* __restrict__ wo)          // [B*Np, 3]
{
  const int pg = blockIdx.x * 256 + threadIdx.x;   // [0, B*Np)
  float b0 = FLT_MAX, b1 = FLT_MAX, b2 = FLT_MAX;
  int   i0 = INT_MAX, i1 = INT_MAX, i2 = INT_MAX;
  size_t base = (size_t)pg * NSEG * 3;
  #pragma unroll
  for (int k = 0; k < NSEG * 3; ++k) {
    float d2 = cd2[base + k];
    int   vi = cidx[base + k];
    bool lt2 = (d2 < b2) || (d2 == b2 && vi < i2);
    if (lt2) {
      bool lt1 = (d2 < b1) || (d2 == b1 && vi < i1);
      if (lt1) {
        b2 = b1; i2 = i1;
        bool lt0 = (d2 < b0) || (d2 == b0 && vi < i0);
        if (lt0) { b1 = b0; i1 = i0; b0 = d2; i0 = vi; }
        else     { b1 = d2; i1 = vi; }
      } else { b2 = d2; i2 = vi; }
    }
  }
  float w0 = 1.0f / (sqrtf(b0) + 1e-8f);
  float w1 = 1.0f / (sqrtf(b1) + 1e-8f);
  float w2 = 1.0f / (sqrtf(b2) + 1e-8f);
  float wsum = (w0 + w1) + w2;
  size_t o = (size_t)pg * 3;
  idxo[o] = i0; idxo[o + 1] = i1; idxo[o + 2] = i2;
  wo[o]   = w0 / wsum; wo[o + 1] = w1 / wsum; wo[o + 2] = w2 / wsum;
}

// ---------------- Gather-interp + per-block channel partial sums ----------------
template <int C, int BDIM>
__global__ __launch_bounds__(BDIM) void interp_kernel(
    const float* __restrict__ voxf,   // [B, Nv, C]
    const int*   __restrict__ idxo,
    const float* __restrict__ wo,
    float* __restrict__ out,          // [B, Np, C]
    float* __restrict__ psum,         // [B, NBLK, C]
    float* __restrict__ psq,
    int Nv)
{
  constexpr int R = BDIM / C;
  const int b = blockIdx.y, blk = blockIdx.x;
  const int tid = threadIdx.x;
  const int r = tid / C, c = tid - r * C;
  const float* fb = voxf + (size_t)b * Nv * C;
  const int PTS = NPOINTS / NBLK;
  const int p0 = blk * PTS;

  float s = 0.f, sq = 0.f;
  for (int p = p0 + r; p < p0 + PTS; p += R) {
    size_t pg = ((size_t)b * NPOINTS + p) * 3;
    int   ia = idxo[pg], ib = idxo[pg + 1], ic = idxo[pg + 2];
    float wa = wo[pg],   wb = wo[pg + 1],   wc = wo[pg + 2];
    float o = wa * fb[(size_t)ia * C + c]
            + wb * fb[(size_t)ib * C + c]
            + wc * fb[(size_t)ic * C + c];
    out[((size_t)b * NPOINTS + p) * C + c] = o;
    s += o; sq += o * o;
  }

  __shared__ float ls[BDIM];
  ls[tid] = s;
  __syncthreads();
  if (r == 0) {
    float tot = s;
    #pragma unroll
    for (int rr = 1; rr < R; ++rr) tot += ls[c + rr * C];
    psum[((size_t)b * NBLK + blk) * C + c] = tot;
  }
  __syncthreads();
  ls[tid] = sq;
  __syncthreads();
  if (r == 0) {
    float tot = sq;
    #pragma unroll
    for (int rr = 1; rr < R; ++rr) tot += ls[c + rr * C];
    psq[((size_t)b * NBLK + blk) * C + c] = tot;
  }
}

// ---------------- BN stats: reduce partials, build scale/shift ----------------
__global__ void bn_stats_kernel(
    const float* __restrict__ psum, const float* __restrict__ psq,
    const float* __restrict__ gamma, const float* __restrict__ beta,
    float* __restrict__ scale, float* __restrict__ shift,
    int nblk, int C, float invN)
{
  const int b = blockIdx.x, c = threadIdx.x;
  float s = 0.f, q = 0.f;
  for (int k = 0; k < nblk; ++k) {
    s += psum[((size_t)b * nblk + k) * C + c];
    q += psq[((size_t)b * nblk + k) * C + c];
  }
  float mu  = s * invN;
  float var = fmaxf(q * invN - mu * mu, 0.f);
  float sc  = gamma[c] * rsqrtf(var + 1e-5f);
  scale[b * C + c] = sc;
  shift[b * C + c] = beta[c] - mu * sc;
}

// ---------------- In-place normalize (float4) ----------------
__global__ __launch_bounds__(256) void bn_apply_kernel(
    float* __restrict__ out, const float* __restrict__ scale,
    const float* __restrict__ shift, int C, int NpC)
{
  const int e = blockIdx.x * 256 + threadIdx.x;   // float4 index over [B, Np*C/4]
  const int npc4 = NpC >> 2, c4n = C >> 2;
  const int b = e / npc4;
  const int rem = e - b * npc4;
  const int c4 = rem % c4n;
  float4 v  = ((float4*)out)[e];
  float4 sc = ((const float4*)scale)[b * c4n + c4];
  float4 sh = ((const float4*)shift)[b * c4n + c4];
  v.x = fmaf(v.x, sc.x, sh.x);
  v.y = fmaf(v.y, sc.y, sh.y);
  v.z = fmaf(v.z, sc.z, sh.z);
  v.w = fmaf(v.w, sc.w, sh.w);
  ((float4*)out)[e] = v;
}

// ---------------- Host launch ----------------
extern "C" void kernel_launch(void* const* d_in, const int* in_sizes, int n_in,
                              void* d_out, int out_size, void* d_ws, size_t ws_size,
                              hipStream_t stream)
{
  const float* ptc = (const float*)d_in[0];
  static const int    Cs[4]     = {256, 128, 96, 96};
  static const int    Nvs[4]    = {2048, 6144, 16384, 32768};
  static const size_t outOff[4] = {0, 16777216, 25165824, 31457280};

  // workspace carve (all offsets 256B aligned); total ~8.1 MB
  char*  w     = (char*)d_ws;
  float* cd2   = (float*)(w);              // 65536*NSEG*3 f32 = 3,145,728 B
  int*   cidx  = (int*)  (w + 3145728);    // 3,145,728 B
  int*   idxo  = (int*)  (w + 6291456);    // 786,432 B
  float* wo    = (float*)(w + 7077888);    // 786,432 B
  float* psum  = (float*)(w + 7864320);    // 131,072 B
  float* psq   = (float*)(w + 7995392);    // 131,072 B
  float* scale = (float*)(w + 8126464);    // 2,048 B
  float* shift = (float*)(w + 8128512);    // 2,048 B

  for (int l = 0; l < 4; ++l) {
    const float* voxc  = (const float*)d_in[1 + 4 * l];
    const float* voxf  = (const float*)d_in[2 + 4 * l];
    const float* gamma = (const float*)d_in[3 + 4 * l];
    const float* beta  = (const float*)d_in[4 + 4 * l];
    const int C = Cs[l], Nv = Nvs[l];
    float* outl = (float*)d_out + outOff[l];

    knn_seg_kernel<<<dim3(NPOINTS / 256, NBATCH, NSEG), 256, 0, stream>>>(
        ptc, voxc, Nv, cd2, cidx);
    knn_merge_kernel<<<(NBATCH * NPOINTS) / 256, 256, 0, stream>>>(
        cd2, cidx, idxo, wo);

    if (C == 256)
      interp_kernel<256, 256><<<dim3(NBLK, NBATCH), 256, 0, stream>>>(
          voxf, idxo, wo, outl, psum, psq, Nv);
    else if (C == 128)
      interp_kernel<128, 256><<<dim3(NBLK, NBATCH), 256, 0, stream>>>(
          voxf, idxo, wo, outl, psum, psq, Nv);
    else
      interp_kernel<96, 192><<<dim3(NBLK, NBATCH), 192, 0, stream>>>(
          voxf, idxo, wo, outl, psum, psq, Nv);

    bn_stats_kernel<<<NBATCH, C, 0, stream>>>(
        psum, psq, gamma, beta, scale, shift, NBLK, C, 1.0f / NPOINTS);

    const int n4 = NBATCH * NPOINTS * C / 4;
    bn_apply_kernel<<<n4 / 256, 256, 0, stream>>>(
        (float*)outl, scale, shift, C, NPOINTS * C);
  }
}

// Round 2
// 1744.975 us; speedup vs baseline: 1.2231x; 1.2231x over previous
//
#include <hip/hip_runtime.h>
#include <cfloat>
#include <climits>
#include <cstdint>

#define NPOINTS 32768
#define NBATCH  2
#define NSEG    16
#define KT      128
#define PP      4
#define NPB     128   // points per interp block

// ---------------- pack voxc [B,Nv,3] -> float4 [B,Nv] ----------------
__global__ __launch_bounds__(256) void pack_kernel(
    const float* __restrict__ voxc, float4* __restrict__ vox4, int n)
{
  int i = blockIdx.x * 256 + threadIdx.x;
  if (i < n)
    vox4[i] = make_float4(voxc[3 * i], voxc[3 * i + 1], voxc[3 * i + 2], 0.f);
}

// ---------------- KNN over a voxel segment: P=4 points/thread, float4 voxels ----------------
__global__ __launch_bounds__(256) void knn_seg_kernel(
    const float*  __restrict__ ptc,   // [B, Np, 3]
    const float4* __restrict__ vox4,  // [B, Nv]
    int Nv,
    float* __restrict__ cd2,          // [NSEG, B*Np, 3]
    int*   __restrict__ cidx)
{
  const int b = blockIdx.y, s = blockIdx.z;
  const int tid = threadIdx.x;
  const int p0 = blockIdx.x * (256 * PP);

  float px[PP], py[PP], pz[PP];
  #pragma unroll
  for (int k = 0; k < PP; ++k) {
    int p = p0 + tid + k * 256;
    const float* pp = ptc + ((size_t)b * NPOINTS + p) * 3;
    px[k] = pp[0]; py[k] = pp[1]; pz[k] = pp[2];
  }

  const int segNv = Nv / NSEG;
  const int v0 = s * segNv;
  const float4* vb = vox4 + (size_t)b * Nv + v0;

  __shared__ float4 sv[KT];

  float bd[PP][3];
  int   bi[PP][3];
  #pragma unroll
  for (int k = 0; k < PP; ++k) {
    bd[k][0] = bd[k][1] = bd[k][2] = FLT_MAX;
    bi[k][0] = bi[k][1] = bi[k][2] = 0;
  }

  for (int t = 0; t < segNv; t += KT) {
    __syncthreads();
    if (tid < KT) sv[tid] = vb[t + tid];
    __syncthreads();
    #pragma unroll 4
    for (int j = 0; j < KT; ++j) {
      float4 vv = sv[j];
      int vi = v0 + t + j;
      #pragma unroll
      for (int k = 0; k < PP; ++k) {
        // exact reference arithmetic: individually-rounded squares, (x2+y2)+z2
        float dx = px[k] - vv.x;
        float dy = py[k] - vv.y;
        float dz = pz[k] - vv.z;
        float d2 = __fadd_rn(__fadd_rn(__fmul_rn(dx, dx), __fmul_rn(dy, dy)),
                             __fmul_rn(dz, dz));
        if (d2 < bd[k][2]) {               // strict <: earlier index wins ties
          if (d2 < bd[k][1]) {
            bd[k][2] = bd[k][1]; bi[k][2] = bi[k][1];
            if (d2 < bd[k][0]) {
              bd[k][1] = bd[k][0]; bi[k][1] = bi[k][0];
              bd[k][0] = d2; bi[k][0] = vi;
            } else { bd[k][1] = d2; bi[k][1] = vi; }
          } else { bd[k][2] = d2; bi[k][2] = vi; }
        }
      }
    }
  }

  #pragma unroll
  for (int k = 0; k < PP; ++k) {
    int p = p0 + tid + k * 256;
    size_t g = (size_t)b * NPOINTS + p;
    size_t base = ((size_t)s * (NBATCH * NPOINTS) + g) * 3;
    cd2[base] = bd[k][0]; cd2[base + 1] = bd[k][1]; cd2[base + 2] = bd[k][2];
    cidx[base] = bi[k][0]; cidx[base + 1] = bi[k][1]; cidx[base + 2] = bi[k][2];
  }
}

// ---------------- Merge NSEG*3 candidates lexicographically by (d2, idx), compute weights ----------------
__global__ __launch_bounds__(256) void knn_merge_kernel(
    const float* __restrict__ cd2, const int* __restrict__ cidx,
    int* __restrict__ idxo, float* __restrict__ wo)
{
  const int g = blockIdx.x * 256 + threadIdx.x;   // [0, B*Np)
  float b0 = FLT_MAX, b1 = FLT_MAX, b2 = FLT_MAX;
  int   i0 = INT_MAX, i1 = INT_MAX, i2 = INT_MAX;
  for (int s = 0; s < NSEG; ++s) {
    size_t base = ((size_t)s * (NBATCH * NPOINTS) + g) * 3;
    #pragma unroll
    for (int j = 0; j < 3; ++j) {
      float d2 = cd2[base + j];
      int   vi = cidx[base + j];
      bool lt2 = (d2 < b2) || (d2 == b2 && vi < i2);
      if (lt2) {
        bool lt1 = (d2 < b1) || (d2 == b1 && vi < i1);
        if (lt1) {
          b2 = b1; i2 = i1;
          bool lt0 = (d2 < b0) || (d2 == b0 && vi < i0);
          if (lt0) { b1 = b0; i1 = i0; b0 = d2; i0 = vi; }
          else     { b1 = d2; i1 = vi; }
        } else { b2 = d2; i2 = vi; }
      }
    }
  }
  float w0 = 1.0f / (sqrtf(b0) + 1e-8f);
  float w1 = 1.0f / (sqrtf(b1) + 1e-8f);
  float w2 = 1.0f / (sqrtf(b2) + 1e-8f);
  float wsum = (w0 + w1) + w2;
  size_t o = (size_t)g * 3;
  idxo[o] = i0; idxo[o + 1] = i1; idxo[o + 2] = i2;
  wo[o]   = w0 / wsum; wo[o + 1] = w1 / wsum; wo[o + 2] = w2 / wsum;
}

// ---------------- Gather-interp (float4) + per-block channel partial sums ----------------
template <int C, int BDIM>
__global__ __launch_bounds__(BDIM) void interp_kernel(
    const float* __restrict__ voxf,   // [B, Nv, C]
    const int*   __restrict__ idxo,
    const float* __restrict__ wo,
    float* __restrict__ out,          // [B, Np, C]
    float* __restrict__ psum,         // [B, nblk, C]
    float* __restrict__ psq,
    int Nv, int nblk)
{
  constexpr int C4 = C / 4;
  constexpr int R  = BDIM / C4;
  const int b = blockIdx.y, blk = blockIdx.x;
  const int tid = threadIdx.x;
  const int r = tid / C4, c4 = tid - r * C4;
  const float4* fb = (const float4*)(voxf + (size_t)b * Nv * C);
  float4* ob = (float4*)(out + (size_t)b * NPOINTS * C);
  const int p0 = blk * NPB;

  float4 s = make_float4(0, 0, 0, 0), q = make_float4(0, 0, 0, 0);
  for (int p = p0 + r; p < p0 + NPB; p += R) {
    size_t pg = ((size_t)b * NPOINTS + p) * 3;
    int   ia = idxo[pg], ib = idxo[pg + 1], ic = idxo[pg + 2];
    float wa = wo[pg],   wb = wo[pg + 1],   wc = wo[pg + 2];
    float4 fa = fb[(size_t)ia * C4 + c4];
    float4 f2 = fb[(size_t)ib * C4 + c4];
    float4 fc = fb[(size_t)ic * C4 + c4];
    float4 o;
    o.x = wa * fa.x + wb * f2.x + wc * fc.x;
    o.y = wa * fa.y + wb * f2.y + wc * fc.y;
    o.z = wa * fa.z + wb * f2.z + wc * fc.z;
    o.w = wa * fa.w + wb * f2.w + wc * fc.w;
    ob[(size_t)p * C4 + c4] = o;
    s.x += o.x; s.y += o.y; s.z += o.z; s.w += o.w;
    q.x += o.x * o.x; q.y += o.y * o.y; q.z += o.z * o.z; q.w += o.w * o.w;
  }

  __shared__ float4 ls[BDIM];
  ls[tid] = s;
  __syncthreads();
  if (r == 0) {
    float4 tot = s;
    #pragma unroll
    for (int rr = 1; rr < R; ++rr) {
      float4 v = ls[c4 + rr * C4];
      tot.x += v.x; tot.y += v.y; tot.z += v.z; tot.w += v.w;
    }
    ((float4*)psum)[((size_t)b * nblk + blk) * C4 + c4] = tot;
  }
  __syncthreads();
  ls[tid] = q;
  __syncthreads();
  if (r == 0) {
    float4 tot = q;
    #pragma unroll
    for (int rr = 1; rr < R; ++rr) {
      float4 v = ls[c4 + rr * C4];
      tot.x += v.x; tot.y += v.y; tot.z += v.z; tot.w += v.w;
    }
    ((float4*)psq)[((size_t)b * nblk + blk) * C4 + c4] = tot;
  }
}

// ---------------- BN stats ----------------
__global__ void bn_stats_kernel(
    const float* __restrict__ psum, const float* __restrict__ psq,
    const float* __restrict__ gamma, const float* __restrict__ beta,
    float* __restrict__ scale, float* __restrict__ shift,
    int nblk, int C, float invN)
{
  const int b = blockIdx.x, c = threadIdx.x;
  float s = 0.f, q = 0.f;
  for (int k = 0; k < nblk; ++k) {
    s += psum[((size_t)b * nblk + k) * C + c];
    q += psq[((size_t)b * nblk + k) * C + c];
  }
  float mu  = s * invN;
  float var = fmaxf(q * invN - mu * mu, 0.f);
  float sc  = gamma[c] * rsqrtf(var + 1e-5f);
  scale[b * C + c] = sc;
  shift[b * C + c] = beta[c] - mu * sc;
}

// ---------------- In-place normalize (float4) ----------------
__global__ __launch_bounds__(256) void bn_apply_kernel(
    float* __restrict__ out, const float* __restrict__ scale,
    const float* __restrict__ shift, int C, int NpC)
{
  const int e = blockIdx.x * 256 + threadIdx.x;
  const int npc4 = NpC >> 2, c4n = C >> 2;
  const int b = e / npc4;
  const int rem = e - b * npc4;
  const int c4 = rem % c4n;
  float4 v  = ((float4*)out)[e];
  float4 sc = ((const float4*)scale)[b * c4n + c4];
  float4 sh = ((const float4*)shift)[b * c4n + c4];
  v.x = fmaf(v.x, sc.x, sh.x);
  v.y = fmaf(v.y, sc.y, sh.y);
  v.z = fmaf(v.z, sc.z, sh.z);
  v.w = fmaf(v.w, sc.w, sh.w);
  ((float4*)out)[e] = v;
}

// ---------------- Host launch ----------------
extern "C" void kernel_launch(void* const* d_in, const int* in_sizes, int n_in,
                              void* d_out, int out_size, void* d_ws, size_t ws_size,
                              hipStream_t stream)
{
  const float* ptc = (const float*)d_in[0];
  static const int    Cs[4]     = {256, 128, 96, 96};
  static const int    Nvs[4]    = {2048, 6144, 16384, 32768};
  static const size_t outOff[4] = {0, 16777216, 25165824, 31457280};

  // ws carve (~3.7 MB): vox4 | idxo | wo | psum | psq | scale | shift
  char*   w     = (char*)d_ws;
  float4* vox4  = (float4*)(w);              // 65536 * 16B = 1,048,576
  int*    idxo  = (int*)   (w + 1048576);    // 786,432
  float*  wo    = (float*) (w + 1835008);    // 786,432
  float*  psum  = (float*) (w + 2621440);    // 524,288 (B*256*256 f32 max)
  float*  psq   = (float*) (w + 3145728);    // 524,288
  float*  scale = (float*) (w + 3670016);    // 2,048
  float*  shift = (float*) (w + 3672064);    // 2,048

  const int nblk = NPOINTS / NPB;            // 256

  for (int l = 0; l < 4; ++l) {
    const float* voxc  = (const float*)d_in[1 + 4 * l];
    const float* voxf  = (const float*)d_in[2 + 4 * l];
    const float* gamma = (const float*)d_in[3 + 4 * l];
    const float* beta  = (const float*)d_in[4 + 4 * l];
    const int C = Cs[l], Nv = Nvs[l];
    float* outl = (float*)d_out + outOff[l];

    // candidate scratch lives in this level's own output region (dead until interp)
    // size: NSEG * 65536 * 3 floats (12.58 MB? no: 3,145,728 f32) + same in ints
    float* cd2  = outl;
    int*   cidx = (int*)(outl + (size_t)NSEG * NBATCH * NPOINTS * 3);

    const int nvox = NBATCH * Nv;
    pack_kernel<<<(nvox + 255) / 256, 256, 0, stream>>>(voxc, vox4, nvox);

    knn_seg_kernel<<<dim3(NPOINTS / (256 * PP), NBATCH, NSEG), 256, 0, stream>>>(
        ptc, vox4, Nv, cd2, cidx);

    knn_merge_kernel<<<(NBATCH * NPOINTS) / 256, 256, 0, stream>>>(
        cd2, cidx, idxo, wo);

    if (C == 256)
      interp_kernel<256, 256><<<dim3(nblk, NBATCH), 256, 0, stream>>>(
          voxf, idxo, wo, outl, psum, psq, Nv, nblk);
    else if (C == 128)
      interp_kernel<128, 256><<<dim3(nblk, NBATCH), 256, 0, stream>>>(
          voxf, idxo, wo, outl, psum, psq, Nv, nblk);
    else
      interp_kernel<96, 240><<<dim3(nblk, NBATCH), 240, 0, stream>>>(
          voxf, idxo, wo, outl, psum, psq, Nv, nblk);

    bn_stats_kernel<<<NBATCH, C, 0, stream>>>(
        psum, psq, gamma, beta, scale, shift, nblk, C, 1.0f / NPOINTS);

    const int n4 = NBATCH * NPOINTS * C / 4;
    bn_apply_kernel<<<n4 / 256, 256, 0, stream>>>(
        (float*)outl, scale, shift, C, NPOINTS * C);
  }
}

// Round 3
// 481.434 us; speedup vs baseline: 4.4333x; 3.6245x over previous
//
#include <hip/hip_runtime.h>
#include <cfloat>
#include <climits>
#include <cstdint>

#define NPOINTS 32768
#define NBATCH  2
#define NLEV    4
#define NPB     128
#define NBLK    (NPOINTS / NPB)   // 256

struct Level {
  const float4* vox4;   // [B, Nv]
  const int*    start;  // [B, ncells+1]
  const int*    binned; // [B, Nv]
  int*          idxo;   // [B*Np*3]
  float*        wo;     // [B*Np*3]
  int G, ncells, Nv;
  float h, invh;
};
struct Params { Level lv[NLEV]; };

__device__ __forceinline__ int cell1d(float x, float invh, int G) {
  int c = (int)(x * invh);
  return min(max(c, 0), G - 1);
}

// ---------------- pack voxc [B,Nv,3] -> float4 ----------------
__global__ __launch_bounds__(256) void pack_kernel(
    const float* __restrict__ voxc, float4* __restrict__ vox4, int n)
{
  int i = blockIdx.x * 256 + threadIdx.x;
  if (i < n)
    vox4[i] = make_float4(voxc[3 * i], voxc[3 * i + 1], voxc[3 * i + 2], 0.f);
}

__global__ __launch_bounds__(256) void zero_kernel(int* __restrict__ p, int n)
{
  int i = blockIdx.x * 256 + threadIdx.x;
  if (i < n) p[i] = 0;
}

// ---------------- bin counts ----------------
__global__ __launch_bounds__(256) void count_kernel(
    const float* __restrict__ voxc, int* __restrict__ cnt,
    int Nv, int G, float invh, int ncells)
{
  int v = blockIdx.x * 256 + threadIdx.x;
  int b = blockIdx.y;
  if (v >= Nv) return;
  const float* p = voxc + ((size_t)b * Nv + v) * 3;
  int cx = cell1d(p[0], invh, G), cy = cell1d(p[1], invh, G), cz = cell1d(p[2], invh, G);
  atomicAdd(&cnt[b * ncells + (cz * G + cy) * G + cx], 1);
}

// ---------------- exclusive scan (one block per batch) ----------------
__global__ __launch_bounds__(1024) void scan_kernel(
    const int* __restrict__ cnt, int* __restrict__ start, int* __restrict__ cur,
    int ncells)
{
  const int b = blockIdx.x, t = threadIdx.x;
  const int* c  = cnt + (size_t)b * ncells;
  int* st = start + (size_t)b * (ncells + 1);
  int* cu = cur + (size_t)b * ncells;
  __shared__ int part[1024];
  const int chunk = (ncells + 1023) / 1024;
  const int lo = t * chunk, hi = min(lo + chunk, ncells);
  int s = 0;
  for (int i = lo; i < hi; ++i) s += c[i];
  part[t] = s;
  __syncthreads();
  for (int off = 1; off < 1024; off <<= 1) {
    int v = (t >= off) ? part[t - off] : 0;
    __syncthreads();
    part[t] += v;
    __syncthreads();
  }
  int base = (t > 0) ? part[t - 1] : 0;
  for (int i = lo; i < hi; ++i) { st[i] = base; cu[i] = base; base += c[i]; }
  if (t == 1023) st[ncells] = part[1023];
}

// ---------------- scatter voxel ids into bins ----------------
__global__ __launch_bounds__(256) void scatter_kernel(
    const float* __restrict__ voxc, int* __restrict__ cur, int* __restrict__ binned,
    int Nv, int G, float invh, int ncells)
{
  int v = blockIdx.x * 256 + threadIdx.x;
  int b = blockIdx.y;
  if (v >= Nv) return;
  const float* p = voxc + ((size_t)b * Nv + v) * 3;
  int cx = cell1d(p[0], invh, G), cy = cell1d(p[1], invh, G), cz = cell1d(p[2], invh, G);
  int pos = atomicAdd(&cur[b * ncells + (cz * G + cy) * G + cx], 1);
  binned[(size_t)b * Nv + pos] = v;
}

// ---------------- fused grid-pruned exact 3-NN query ----------------
__global__ __launch_bounds__(256) void query_kernel(
    const float* __restrict__ ptc, Params prm)
{
  const int l = blockIdx.y, b = blockIdx.z;
  const Level L = prm.lv[l];
  const int p = blockIdx.x * 256 + threadIdx.x;
  const float* pp = ptc + ((size_t)b * NPOINTS + p) * 3;
  const float px = pp[0], py = pp[1], pz = pp[2];
  const int G = L.G;
  const float h = L.h;

  const int cx = cell1d(px, L.invh, G);
  const int cy = cell1d(py, L.invh, G);
  const int cz = cell1d(pz, L.invh, G);
  const float fx = px - cx * h, fy = py - cy * h, fz = pz - cz * h;
  float m = fminf(fminf(fminf(fx, h - fx), fminf(fy, h - fy)), fminf(fz, h - fz));
  m = fmaxf(m, 0.f);

  const int* start  = L.start  + (size_t)b * (L.ncells + 1);
  const int* binned = L.binned + (size_t)b * L.Nv;
  const float4* vb  = L.vox4   + (size_t)b * L.Nv;

  float b0 = FLT_MAX, b1 = FLT_MAX, b2 = FLT_MAX;
  int   i0 = INT_MAX, i1 = INT_MAX, i2 = INT_MAX;

  auto cand = [&](int vi) {
    float4 vv = vb[vi];
    // exact reference arithmetic: individually-rounded squares, (x2+y2)+z2
    float dx = px - vv.x, dy = py - vv.y, dz = pz - vv.z;
    float d2 = __fadd_rn(__fadd_rn(__fmul_rn(dx, dx), __fmul_rn(dy, dy)),
                         __fmul_rn(dz, dz));
    if (d2 < b2 || (d2 == b2 && vi < i2)) {
      if (d2 < b1 || (d2 == b1 && vi < i1)) {
        b2 = b1; i2 = i1;
        if (d2 < b0 || (d2 == b0 && vi < i0)) { b1 = b0; i1 = i0; b0 = d2; i0 = vi; }
        else                                  { b1 = d2; i1 = vi; }
      } else { b2 = d2; i2 = vi; }
    }
  };

  const int rmax = max(max(cx, G - 1 - cx), max(max(cy, G - 1 - cy), max(cz, G - 1 - cz)));
  for (int rho = 0; rho <= rmax; ++rho) {
    if (rho >= 1) {
      float dmin = fmaxf((rho - 1) * h + m, 0.f);
      if (dmin * dmin * 0.99999f > b2) break;   // conservative exact-prune bound
    }
    const int z0 = max(cz - rho, 0), z1 = min(cz + rho, G - 1);
    const int y0 = max(cy - rho, 0), y1 = min(cy + rho, G - 1);
    for (int iz = z0; iz <= z1; ++iz) {
      const int adz = abs(iz - cz);
      for (int iy = y0; iy <= y1; ++iy) {
        const int ady = max(adz, abs(iy - cy));
        const int row = (iz * G + iy) * G;
        if (ady == rho) {
          // whole x-extent is on the shell; bins are contiguous along x
          const int x0 = max(cx - rho, 0), x1 = min(cx + rho, G - 1);
          const int ks = start[row + x0], ke = start[row + x1 + 1];
          for (int k = ks; k < ke; ++k) cand(binned[k]);
        } else {
          const int xl = cx - rho, xr = cx + rho;
          if (xl >= 0) {
            const int ks = start[row + xl], ke = start[row + xl + 1];
            for (int k = ks; k < ke; ++k) cand(binned[k]);
          }
          if (xr <= G - 1) {
            const int ks = start[row + xr], ke = start[row + xr + 1];
            for (int k = ks; k < ke; ++k) cand(binned[k]);
          }
        }
      }
    }
  }

  float w0 = 1.0f / (sqrtf(b0) + 1e-8f);
  float w1 = 1.0f / (sqrtf(b1) + 1e-8f);
  float w2 = 1.0f / (sqrtf(b2) + 1e-8f);
  float ws = (w0 + w1) + w2;
  size_t o = ((size_t)b * NPOINTS + p) * 3;
  L.idxo[o] = i0; L.idxo[o + 1] = i1; L.idxo[o + 2] = i2;
  L.wo[o] = w0 / ws; L.wo[o + 1] = w1 / ws; L.wo[o + 2] = w2 / ws;
}

// ---------------- Gather-interp (float4) + per-block channel partial sums ----------------
template <int C, int BDIM>
__global__ __launch_bounds__(BDIM) void interp_kernel(
    const float* __restrict__ voxf, const int* __restrict__ idxo,
    const float* __restrict__ wo, float* __restrict__ out,
    float* __restrict__ psum, float* __restrict__ psq, int Nv)
{
  constexpr int C4 = C / 4;
  constexpr int R  = BDIM / C4;
  const int b = blockIdx.y, blk = blockIdx.x;
  const int tid = threadIdx.x;
  const int r = tid / C4, c4 = tid - r * C4;
  const float4* fb = (const float4*)(voxf + (size_t)b * Nv * C);
  float4* ob = (float4*)(out + (size_t)b * NPOINTS * C);
  const int p0 = blk * NPB;

  float4 s = make_float4(0, 0, 0, 0), q = make_float4(0, 0, 0, 0);
  for (int p = p0 + r; p < p0 + NPB; p += R) {
    size_t pg = ((size_t)b * NPOINTS + p) * 3;
    int   ia = idxo[pg], ib = idxo[pg + 1], ic = idxo[pg + 2];
    float wa = wo[pg],   wb = wo[pg + 1],   wc = wo[pg + 2];
    float4 fa = fb[(size_t)ia * C4 + c4];
    float4 f2 = fb[(size_t)ib * C4 + c4];
    float4 fc = fb[(size_t)ic * C4 + c4];
    float4 o;
    o.x = wa * fa.x + wb * f2.x + wc * fc.x;
    o.y = wa * fa.y + wb * f2.y + wc * fc.y;
    o.z = wa * fa.z + wb * f2.z + wc * fc.z;
    o.w = wa * fa.w + wb * f2.w + wc * fc.w;
    ob[(size_t)p * C4 + c4] = o;
    s.x += o.x; s.y += o.y; s.z += o.z; s.w += o.w;
    q.x += o.x * o.x; q.y += o.y * o.y; q.z += o.z * o.z; q.w += o.w * o.w;
  }

  __shared__ float4 ls[BDIM];
  ls[tid] = s;
  __syncthreads();
  if (r == 0) {
    float4 tot = s;
    #pragma unroll
    for (int rr = 1; rr < R; ++rr) {
      float4 v = ls[c4 + rr * C4];
      tot.x += v.x; tot.y += v.y; tot.z += v.z; tot.w += v.w;
    }
    ((float4*)psum)[((size_t)b * NBLK + blk) * C4 + c4] = tot;
  }
  __syncthreads();
  ls[tid] = q;
  __syncthreads();
  if (r == 0) {
    float4 tot = q;
    #pragma unroll
    for (int rr = 1; rr < R; ++rr) {
      float4 v = ls[c4 + rr * C4];
      tot.x += v.x; tot.y += v.y; tot.z += v.z; tot.w += v.w;
    }
    ((float4*)psq)[((size_t)b * NBLK + blk) * C4 + c4] = tot;
  }
}

// ---------------- BN stats (parallel reduce over NBLK partials) ----------------
__global__ __launch_bounds__(256) void bn_stats_kernel(
    const float* __restrict__ psum, const float* __restrict__ psq,
    const float* __restrict__ gamma, const float* __restrict__ beta,
    float* __restrict__ scale, float* __restrict__ shift, int C, float invN)
{
  const int c = blockIdx.x, b = blockIdx.y, t = threadIdx.x;
  float s = 0.f, q = 0.f;
  for (int k = t; k < NBLK; k += 256) {
    s += psum[((size_t)b * NBLK + k) * C + c];
    q += psq[((size_t)b * NBLK + k) * C + c];
  }
  __shared__ float ss[256], qs[256];
  ss[t] = s; qs[t] = q;
  __syncthreads();
  for (int o = 128; o > 0; o >>= 1) {
    if (t < o) { ss[t] += ss[t + o]; qs[t] += qs[t + o]; }
    __syncthreads();
  }
  if (t == 0) {
    float mu  = ss[0] * invN;
    float var = fmaxf(qs[0] * invN - mu * mu, 0.f);
    float sc  = gamma[c] * rsqrtf(var + 1e-5f);
    scale[b * C + c] = sc;
    shift[b * C + c] = beta[c] - mu * sc;
  }
}

// ---------------- In-place normalize (float4) ----------------
__global__ __launch_bounds__(256) void bn_apply_kernel(
    float* __restrict__ out, const float* __restrict__ scale,
    const float* __restrict__ shift, int C, int NpC)
{
  const int e = blockIdx.x * 256 + threadIdx.x;
  const int npc4 = NpC >> 2, c4n = C >> 2;
  const int b = e / npc4;
  const int rem = e - b * npc4;
  const int c4 = rem % c4n;
  float4 v  = ((float4*)out)[e];
  float4 sc = ((const float4*)scale)[b * c4n + c4];
  float4 sh = ((const float4*)shift)[b * c4n + c4];
  v.x = fmaf(v.x, sc.x, sh.x);
  v.y = fmaf(v.y, sc.y, sh.y);
  v.z = fmaf(v.z, sc.z, sh.z);
  v.w = fmaf(v.w, sc.w, sh.w);
  ((float4*)out)[e] = v;
}

// ---------------- Host launch ----------------
extern "C" void kernel_launch(void* const* d_in, const int* in_sizes, int n_in,
                              void* d_out, int out_size, void* d_ws, size_t ws_size,
                              hipStream_t stream)
{
  const float* ptc = (const float*)d_in[0];
  static const int    Cs[4]     = {256, 128, 96, 96};
  static const int    Nvs[4]    = {2048, 6144, 16384, 32768};
  static const int    Gs[4]     = {10, 14, 18, 22};
  static const size_t outOff[4] = {0, 16777216, 25165824, 31457280};

  // ---- workspace carve (~10.2 MB) ----
  size_t off = 0;
  auto carve = [&](size_t bytes) {
    off = (off + 255) & ~(size_t)255;
    size_t o = off; off += bytes; return o;
  };
  float4* vox4[4]; int* cnt[4]; int* stt[4]; int* cur[4]; int* bin[4];
  int nc[4];
  char* w = (char*)d_ws;
  for (int l = 0; l < 4; ++l) {
    nc[l] = Gs[l] * Gs[l] * Gs[l];
    vox4[l] = (float4*)(w + carve((size_t)NBATCH * Nvs[l] * 16));
    cnt[l]  = (int*)  (w + carve((size_t)NBATCH * nc[l] * 4));
    stt[l]  = (int*)  (w + carve((size_t)NBATCH * (nc[l] + 1) * 4));
    cur[l]  = (int*)  (w + carve((size_t)NBATCH * nc[l] * 4));
    bin[l]  = (int*)  (w + carve((size_t)NBATCH * Nvs[l] * 4));
  }
  int*   idxo  = (int*)  (w + carve((size_t)NLEV * NBATCH * NPOINTS * 3 * 4));
  float* wo    = (float*)(w + carve((size_t)NLEV * NBATCH * NPOINTS * 3 * 4));
  float* psum  = (float*)(w + carve((size_t)NBATCH * NBLK * 256 * 4));
  float* psq   = (float*)(w + carve((size_t)NBATCH * NBLK * 256 * 4));
  float* scale = (float*)(w + carve((size_t)NBATCH * 256 * 4));
  float* shift = (float*)(w + carve((size_t)NBATCH * 256 * 4));

  Params prm;
  for (int l = 0; l < 4; ++l) {
    Level& L = prm.lv[l];
    L.vox4 = vox4[l]; L.start = stt[l]; L.binned = bin[l];
    L.idxo = idxo + (size_t)l * NBATCH * NPOINTS * 3;
    L.wo   = wo   + (size_t)l * NBATCH * NPOINTS * 3;
    L.G = Gs[l]; L.ncells = nc[l]; L.Nv = Nvs[l];
    L.h = 50.0f / Gs[l]; L.invh = Gs[l] / 50.0f;
  }

  // ---- binning ----
  for (int l = 0; l < 4; ++l) {
    const float* voxc = (const float*)d_in[1 + 4 * l];
    const int nvox = NBATCH * Nvs[l];
    pack_kernel<<<(nvox + 255) / 256, 256, 0, stream>>>(voxc, vox4[l], nvox);
    zero_kernel<<<(NBATCH * nc[l] + 255) / 256, 256, 0, stream>>>(cnt[l], NBATCH * nc[l]);
    count_kernel<<<dim3((Nvs[l] + 255) / 256, NBATCH), 256, 0, stream>>>(
        voxc, cnt[l], Nvs[l], Gs[l], prm.lv[l].invh, nc[l]);
    scan_kernel<<<NBATCH, 1024, 0, stream>>>(cnt[l], stt[l], cur[l], nc[l]);
    scatter_kernel<<<dim3((Nvs[l] + 255) / 256, NBATCH), 256, 0, stream>>>(
        voxc, cur[l], bin[l], Nvs[l], Gs[l], prm.lv[l].invh, nc[l]);
  }

  // ---- fused exact 3-NN query over all levels ----
  query_kernel<<<dim3(NPOINTS / 256, NLEV, NBATCH), 256, 0, stream>>>(ptc, prm);

  // ---- per-level interp + BN ----
  for (int l = 0; l < 4; ++l) {
    const float* voxf  = (const float*)d_in[2 + 4 * l];
    const float* gamma = (const float*)d_in[3 + 4 * l];
    const float* beta  = (const float*)d_in[4 + 4 * l];
    const int C = Cs[l], Nv = Nvs[l];
    float* outl = (float*)d_out + outOff[l];
    const int* idl = idxo + (size_t)l * NBATCH * NPOINTS * 3;
    const float* wl = wo  + (size_t)l * NBATCH * NPOINTS * 3;

    if (C == 256)
      interp_kernel<256, 256><<<dim3(NBLK, NBATCH), 256, 0, stream>>>(
          voxf, idl, wl, outl, psum, psq, Nv);
    else if (C == 128)
      interp_kernel<128, 256><<<dim3(NBLK, NBATCH), 256, 0, stream>>>(
          voxf, idl, wl, outl, psum, psq, Nv);
    else
      interp_kernel<96, 240><<<dim3(NBLK, NBATCH), 240, 0, stream>>>(
          voxf, idl, wl, outl, psum, psq, Nv);

    bn_stats_kernel<<<dim3(C, NBATCH), 256, 0, stream>>>(
        psum, psq, gamma, beta, scale, shift, C, 1.0f / NPOINTS);

    const int n4 = NBATCH * NPOINTS * C / 4;
    bn_apply_kernel<<<n4 / 256, 256, 0, stream>>>(
        (float*)outl, scale, shift, C, NPOINTS * C);
  }
}

// Round 4
// 389.665 us; speedup vs baseline: 5.4773x; 1.2355x over previous
//
#include <hip/hip_runtime.h>
#include <cfloat>
#include <climits>
#include <cstdint>

#define NPOINTS 32768
#define NBATCH  2
#define NLEV    4
#define NPB     128
#define NBLK    (NPOINTS / NPB)   // 256

struct Level {
  const float4* sorted;  // [B, Nv] coords in bin order, .w = bit-cast original idx
  const int*    start;   // [B, ncells+1]
  int*          idxo;    // [B*Np*3]
  float*        wo;      // [B*Np*3]
  int G, ncells, Nv;
  float h, invh;
};
struct Params { Level lv[NLEV]; };

__device__ __forceinline__ int cell1d(float x, float invh, int G) {
  int c = (int)(x * invh);
  return min(max(c, 0), G - 1);
}

__global__ __launch_bounds__(256) void zero_kernel(int* __restrict__ p, int n)
{
  int i = blockIdx.x * 256 + threadIdx.x;
  if (i < n) p[i] = 0;
}

// ---------------- bin counts ----------------
__global__ __launch_bounds__(256) void count_kernel(
    const float* __restrict__ voxc, int* __restrict__ cnt,
    int Nv, int G, float invh, int ncells)
{
  int v = blockIdx.x * 256 + threadIdx.x;
  int b = blockIdx.y;
  if (v >= Nv) return;
  const float* p = voxc + ((size_t)b * Nv + v) * 3;
  int cx = cell1d(p[0], invh, G), cy = cell1d(p[1], invh, G), cz = cell1d(p[2], invh, G);
  atomicAdd(&cnt[b * ncells + (cz * G + cy) * G + cx], 1);
}

// ---------------- exclusive scan (one block per batch) ----------------
__global__ __launch_bounds__(1024) void scan_kernel(
    const int* __restrict__ cnt, int* __restrict__ start, int* __restrict__ cur,
    int ncells)
{
  const int b = blockIdx.x, t = threadIdx.x;
  const int* c  = cnt + (size_t)b * ncells;
  int* st = start + (size_t)b * (ncells + 1);
  int* cu = cur + (size_t)b * ncells;
  __shared__ int part[1024];
  const int chunk = (ncells + 1023) / 1024;
  const int lo = t * chunk, hi = min(lo + chunk, ncells);
  int s = 0;
  for (int i = lo; i < hi; ++i) s += c[i];
  part[t] = s;
  __syncthreads();
  for (int off = 1; off < 1024; off <<= 1) {
    int v = (t >= off) ? part[t - off] : 0;
    __syncthreads();
    part[t] += v;
    __syncthreads();
  }
  int base = (t > 0) ? part[t - 1] : 0;
  for (int i = lo; i < hi; ++i) { st[i] = base; cu[i] = base; base += c[i]; }
  if (t == 1023) st[ncells] = part[1023];
}

// ---------------- scatter: packed coords+idx into bin order ----------------
__global__ __launch_bounds__(256) void scatter_kernel(
    const float* __restrict__ voxc, int* __restrict__ cur,
    float4* __restrict__ sorted, int Nv, int G, float invh, int ncells)
{
  int v = blockIdx.x * 256 + threadIdx.x;
  int b = blockIdx.y;
  if (v >= Nv) return;
  const float* p = voxc + ((size_t)b * Nv + v) * 3;
  float x = p[0], y = p[1], z = p[2];
  int cx = cell1d(x, invh, G), cy = cell1d(y, invh, G), cz = cell1d(z, invh, G);
  int pos = atomicAdd(&cur[b * ncells + (cz * G + cy) * G + cx], 1);
  sorted[(size_t)b * Nv + pos] = make_float4(x, y, z, __int_as_float(v));
}

// ---------------- fused grid-pruned exact 3-NN query, 4 lanes per point ----------------
__global__ __launch_bounds__(256) void query_kernel(
    const float* __restrict__ ptc, Params prm)
{
  const int l = blockIdx.y, b = blockIdx.z;
  const Level L = prm.lv[l];
  const int tid = threadIdx.x;
  const int q = tid & 3;                       // quad lane
  const int p = blockIdx.x * 64 + (tid >> 2);  // point id
  const float* pp = ptc + ((size_t)b * NPOINTS + p) * 3;
  const float px = pp[0], py = pp[1], pz = pp[2];
  const int G = L.G;
  const float h = L.h;

  const int cx = cell1d(px, L.invh, G);
  const int cy = cell1d(py, L.invh, G);
  const int cz = cell1d(pz, L.invh, G);
  const float fx = px - cx * h, fy = py - cy * h, fz = pz - cz * h;
  float m = fminf(fminf(fminf(fx, h - fx), fminf(fy, h - fy)), fminf(fz, h - fz));
  m = fmaxf(m, 0.f);

  const int* start     = L.start  + (size_t)b * (L.ncells + 1);
  const float4* sorted = L.sorted + (size_t)b * L.Nv;

  float b0 = FLT_MAX, b1 = FLT_MAX, b2 = FLT_MAX;
  int   i0 = INT_MAX, i1 = INT_MAX, i2 = INT_MAX;

  auto ins = [&](float d2, int vi) {
    if (d2 < b2 || (d2 == b2 && vi < i2)) {
      if (d2 < b1 || (d2 == b1 && vi < i1)) {
        b2 = b1; i2 = i1;
        if (d2 < b0 || (d2 == b0 && vi < i0)) { b1 = b0; i1 = i0; b0 = d2; i0 = vi; }
        else                                  { b1 = d2; i1 = vi; }
      } else { b2 = d2; i2 = vi; }
    }
  };
  auto cand = [&](int k) {
    float4 vv = sorted[k];
    int vi = __float_as_int(vv.w);
    // exact reference arithmetic: individually-rounded squares, (x2+y2)+z2
    float dx = px - vv.x, dy = py - vv.y, dz = pz - vv.z;
    float d2 = __fadd_rn(__fadd_rn(__fmul_rn(dx, dx), __fmul_rn(dy, dy)),
                         __fmul_rn(dz, dz));
    ins(d2, vi);
  };
  auto scan_range = [&](int ks, int ke) {
    for (int k = ks + q; k < ke; k += 4) cand(k);
  };

  const int rmax = max(max(cx, G - 1 - cx), max(max(cy, G - 1 - cy), max(cz, G - 1 - cz)));
  for (int rho = 0; rho <= rmax; ++rho) {
    if (rho >= 1) {
      // quad-wide valid bound: union's true b2 <= min over lanes of local b2
      float bm = fminf(b2, __shfl_xor(b2, 1));
      bm = fminf(bm, __shfl_xor(bm, 2));
      float dmin = fmaxf((rho - 1) * h + m, 0.f);
      if (dmin * dmin * 0.99999f > bm) break;   // conservative exact-prune bound
    }
    const int z0 = max(cz - rho, 0), z1 = min(cz + rho, G - 1);
    const int y0 = max(cy - rho, 0), y1 = min(cy + rho, G - 1);
    for (int iz = z0; iz <= z1; ++iz) {
      const int adz = abs(iz - cz);
      for (int iy = y0; iy <= y1; ++iy) {
        const int ady = max(adz, abs(iy - cy));
        const int row = (iz * G + iy) * G;
        if (ady == rho) {
          const int x0 = max(cx - rho, 0), x1 = min(cx + rho, G - 1);
          scan_range(start[row + x0], start[row + x1 + 1]);
        } else {
          const int xl = cx - rho, xr = cx + rho;
          if (xl >= 0)     scan_range(start[row + xl], start[row + xl + 1]);
          if (xr <= G - 1) scan_range(start[row + xr], start[row + xr + 1]);
        }
      }
    }
  }

  // merge the 4 lanes' sorted triples (deterministic, lex (d2, idx))
  #pragma unroll
  for (int mask = 1; mask <= 2; mask <<= 1) {
    float c0 = __shfl_xor(b0, mask), c1 = __shfl_xor(b1, mask), c2 = __shfl_xor(b2, mask);
    int   j0 = __shfl_xor(i0, mask), j1 = __shfl_xor(i1, mask), j2 = __shfl_xor(i2, mask);
    ins(c0, j0); ins(c1, j1); ins(c2, j2);
  }

  if (q == 0) {
    float w0 = 1.0f / (sqrtf(b0) + 1e-8f);
    float w1 = 1.0f / (sqrtf(b1) + 1e-8f);
    float w2 = 1.0f / (sqrtf(b2) + 1e-8f);
    float ws = (w0 + w1) + w2;
    size_t o = ((size_t)b * NPOINTS + p) * 3;
    L.idxo[o] = i0; L.idxo[o + 1] = i1; L.idxo[o + 2] = i2;
    L.wo[o] = w0 / ws; L.wo[o + 1] = w1 / ws; L.wo[o + 2] = w2 / ws;
  }
}

// ---------------- Gather-interp (float4) + per-block channel partial sums ----------------
template <int C, int BDIM>
__global__ __launch_bounds__(BDIM) void interp_kernel(
    const float* __restrict__ voxf, const int* __restrict__ idxo,
    const float* __restrict__ wo, float* __restrict__ out,
    float* __restrict__ psum, float* __restrict__ psq, int Nv)
{
  constexpr int C4 = C / 4;
  constexpr int R  = BDIM / C4;
  const int b = blockIdx.y, blk = blockIdx.x;
  const int tid = threadIdx.x;
  const int r = tid / C4, c4 = tid - r * C4;
  const float4* fb = (const float4*)(voxf + (size_t)b * Nv * C);
  float4* ob = (float4*)(out + (size_t)b * NPOINTS * C);
  const int p0 = blk * NPB;

  float4 s = make_float4(0, 0, 0, 0), q = make_float4(0, 0, 0, 0);
  for (int p = p0 + r; p < p0 + NPB; p += R) {
    size_t pg = ((size_t)b * NPOINTS + p) * 3;
    int   ia = idxo[pg], ib = idxo[pg + 1], ic = idxo[pg + 2];
    float wa = wo[pg],   wb = wo[pg + 1],   wc = wo[pg + 2];
    float4 fa = fb[(size_t)ia * C4 + c4];
    float4 f2 = fb[(size_t)ib * C4 + c4];
    float4 fc = fb[(size_t)ic * C4 + c4];
    float4 o;
    o.x = wa * fa.x + wb * f2.x + wc * fc.x;
    o.y = wa * fa.y + wb * f2.y + wc * fc.y;
    o.z = wa * fa.z + wb * f2.z + wc * fc.z;
    o.w = wa * fa.w + wb * f2.w + wc * fc.w;
    ob[(size_t)p * C4 + c4] = o;
    s.x += o.x; s.y += o.y; s.z += o.z; s.w += o.w;
    q.x += o.x * o.x; q.y += o.y * o.y; q.z += o.z * o.z; q.w += o.w * o.w;
  }

  __shared__ float4 ls[BDIM];
  ls[tid] = s;
  __syncthreads();
  if (r == 0) {
    float4 tot = s;
    #pragma unroll
    for (int rr = 1; rr < R; ++rr) {
      float4 v = ls[c4 + rr * C4];
      tot.x += v.x; tot.y += v.y; tot.z += v.z; tot.w += v.w;
    }
    ((float4*)psum)[((size_t)b * NBLK + blk) * C4 + c4] = tot;
  }
  __syncthreads();
  ls[tid] = q;
  __syncthreads();
  if (r == 0) {
    float4 tot = q;
    #pragma unroll
    for (int rr = 1; rr < R; ++rr) {
      float4 v = ls[c4 + rr * C4];
      tot.x += v.x; tot.y += v.y; tot.z += v.z; tot.w += v.w;
    }
    ((float4*)psq)[((size_t)b * NBLK + blk) * C4 + c4] = tot;
  }
}

// ---------------- BN stats (parallel reduce over NBLK partials) ----------------
__global__ __launch_bounds__(256) void bn_stats_kernel(
    const float* __restrict__ psum, const float* __restrict__ psq,
    const float* __restrict__ gamma, const float* __restrict__ beta,
    float* __restrict__ scale, float* __restrict__ shift, int C, float invN)
{
  const int c = blockIdx.x, b = blockIdx.y, t = threadIdx.x;
  float s = 0.f, q = 0.f;
  for (int k = t; k < NBLK; k += 256) {
    s += psum[((size_t)b * NBLK + k) * C + c];
    q += psq[((size_t)b * NBLK + k) * C + c];
  }
  __shared__ float ss[256], qs[256];
  ss[t] = s; qs[t] = q;
  __syncthreads();
  for (int o = 128; o > 0; o >>= 1) {
    if (t < o) { ss[t] += ss[t + o]; qs[t] += qs[t + o]; }
    __syncthreads();
  }
  if (t == 0) {
    float mu  = ss[0] * invN;
    float var = fmaxf(qs[0] * invN - mu * mu, 0.f);
    float sc  = gamma[c] * rsqrtf(var + 1e-5f);
    scale[b * C + c] = sc;
    shift[b * C + c] = beta[c] - mu * sc;
  }
}

// ---------------- In-place normalize (float4) ----------------
__global__ __launch_bounds__(256) void bn_apply_kernel(
    float* __restrict__ out, const float* __restrict__ scale,
    const float* __restrict__ shift, int C, int NpC)
{
  const int e = blockIdx.x * 256 + threadIdx.x;
  const int npc4 = NpC >> 2, c4n = C >> 2;
  const int b = e / npc4;
  const int rem = e - b * npc4;
  const int c4 = rem % c4n;
  float4 v  = ((float4*)out)[e];
  float4 sc = ((const float4*)scale)[b * c4n + c4];
  float4 sh = ((const float4*)shift)[b * c4n + c4];
  v.x = fmaf(v.x, sc.x, sh.x);
  v.y = fmaf(v.y, sc.y, sh.y);
  v.z = fmaf(v.z, sc.z, sh.z);
  v.w = fmaf(v.w, sc.w, sh.w);
  ((float4*)out)[e] = v;
}

// ---------------- Host launch ----------------
extern "C" void kernel_launch(void* const* d_in, const int* in_sizes, int n_in,
                              void* d_out, int out_size, void* d_ws, size_t ws_size,
                              hipStream_t stream)
{
  const float* ptc = (const float*)d_in[0];
  static const int    Cs[4]     = {256, 128, 96, 96};
  static const int    Nvs[4]    = {2048, 6144, 16384, 32768};
  static const int    Gs[4]     = {10, 14, 18, 22};
  static const size_t outOff[4] = {0, 16777216, 25165824, 31457280};

  // ---- workspace carve (~6 MB) ----
  size_t off = 0;
  auto carve = [&](size_t bytes) {
    off = (off + 255) & ~(size_t)255;
    size_t o = off; off += bytes; return o;
  };
  float4* sorted[4]; int* cnt[4]; int* stt[4]; int* cur[4];
  int nc[4];
  char* w = (char*)d_ws;
  for (int l = 0; l < 4; ++l) {
    nc[l] = Gs[l] * Gs[l] * Gs[l];
    sorted[l] = (float4*)(w + carve((size_t)NBATCH * Nvs[l] * 16));
    cnt[l]    = (int*)   (w + carve((size_t)NBATCH * nc[l] * 4));
    stt[l]    = (int*)   (w + carve((size_t)NBATCH * (nc[l] + 1) * 4));
    cur[l]    = (int*)   (w + carve((size_t)NBATCH * nc[l] * 4));
  }
  int*   idxo  = (int*)  (w + carve((size_t)NLEV * NBATCH * NPOINTS * 3 * 4));
  float* wo    = (float*)(w + carve((size_t)NLEV * NBATCH * NPOINTS * 3 * 4));
  float* psum  = (float*)(w + carve((size_t)NBATCH * NBLK * 256 * 4));
  float* psq   = (float*)(w + carve((size_t)NBATCH * NBLK * 256 * 4));
  float* scale = (float*)(w + carve((size_t)NBATCH * 256 * 4));
  float* shift = (float*)(w + carve((size_t)NBATCH * 256 * 4));

  Params prm;
  for (int l = 0; l < 4; ++l) {
    Level& L = prm.lv[l];
    L.sorted = sorted[l]; L.start = stt[l];
    L.idxo = idxo + (size_t)l * NBATCH * NPOINTS * 3;
    L.wo   = wo   + (size_t)l * NBATCH * NPOINTS * 3;
    L.G = Gs[l]; L.ncells = nc[l]; L.Nv = Nvs[l];
    L.h = 50.0f / Gs[l]; L.invh = Gs[l] / 50.0f;
  }

  // ---- binning ----
  for (int l = 0; l < 4; ++l) {
    const float* voxc = (const float*)d_in[1 + 4 * l];
    zero_kernel<<<(NBATCH * nc[l] + 255) / 256, 256, 0, stream>>>(cnt[l], NBATCH * nc[l]);
    count_kernel<<<dim3((Nvs[l] + 255) / 256, NBATCH), 256, 0, stream>>>(
        voxc, cnt[l], Nvs[l], Gs[l], prm.lv[l].invh, nc[l]);
    scan_kernel<<<NBATCH, 1024, 0, stream>>>(cnt[l], stt[l], cur[l], nc[l]);
    scatter_kernel<<<dim3((Nvs[l] + 255) / 256, NBATCH), 256, 0, stream>>>(
        voxc, cur[l], sorted[l], Nvs[l], Gs[l], prm.lv[l].invh, nc[l]);
  }

  // ---- fused exact 3-NN query over all levels (4 lanes per point) ----
  query_kernel<<<dim3(NPOINTS / 64, NLEV, NBATCH), 256, 0, stream>>>(ptc, prm);

  // ---- per-level interp + BN ----
  for (int l = 0; l < 4; ++l) {
    const float* voxf  = (const float*)d_in[2 + 4 * l];
    const float* gamma = (const float*)d_in[3 + 4 * l];
    const float* beta  = (const float*)d_in[4 + 4 * l];
    const int C = Cs[l], Nv = Nvs[l];
    float* outl = (float*)d_out + outOff[l];
    const int* idl = idxo + (size_t)l * NBATCH * NPOINTS * 3;
    const float* wl = wo  + (size_t)l * NBATCH * NPOINTS * 3;

    if (C == 256)
      interp_kernel<256, 256><<<dim3(NBLK, NBATCH), 256, 0, stream>>>(
          voxf, idl, wl, outl, psum, psq, Nv);
    else if (C == 128)
      interp_kernel<128, 256><<<dim3(NBLK, NBATCH), 256, 0, stream>>>(
          voxf, idl, wl, outl, psum, psq, Nv);
    else
      interp_kernel<96, 240><<<dim3(NBLK, NBATCH), 240, 0, stream>>>(
          voxf, idl, wl, outl, psum, psq, Nv);

    bn_stats_kernel<<<dim3(C, NBATCH), 256, 0, stream>>>(
        psum, psq, gamma, beta, scale, shift, C, 1.0f / NPOINTS);

    const int n4 = NBATCH * NPOINTS * C / 4;
    bn_apply_kernel<<<n4 / 256, 256, 0, stream>>>(
        (float*)outl, scale, shift, C, NPOINTS * C);
  }
}

// Round 5
// 338.896 us; speedup vs baseline: 6.2979x; 1.1498x over previous
//
#include <hip/hip_runtime.h>
#include <cfloat>
#include <climits>
#include <cstdint>

#define NPOINTS 32768
#define NBATCH  2
#define NLEV    4
#define NJOB    5          // 4 voxel levels + 1 point sort
#define PG      16         // point-sort grid
#define PCELLS  (PG*PG*PG)
#define NPB     128
#define NBLK    (NPOINTS / NPB)   // 256

struct BinJob {
  const float* coords;   // [B, N, 3]
  int* cnt; int* start; int* cur;
  float4* sorted;        // [B, N] {x,y,z,bitcast(idx)} in bin order
  int G, ncells, N;
  float invh;
};
struct BinParams { BinJob job[NJOB]; };

struct Level {
  const float4* sorted;  // [B, Nv] coords in bin order, .w = bit-cast original idx
  const int*    start;   // [B, ncells+1]
  int*          idxo;    // [B*Np*3]
  float*        wo;      // [B*Np*3]
  int G, ncells, Nv;
  float h, invh;
};
struct Params { Level lv[NLEV]; };

__device__ __forceinline__ int cell1d(float x, float invh, int G) {
  int c = (int)(x * invh);
  return min(max(c, 0), G - 1);
}

__global__ __launch_bounds__(256) void zero_kernel(int* __restrict__ p, int n)
{
  int i = blockIdx.x * 256 + threadIdx.x;
  if (i < n) p[i] = 0;
}

// ---------------- fused bin counts (all jobs) ----------------
__global__ __launch_bounds__(256) void count_kernel(BinParams prm)
{
  const BinJob J = prm.job[blockIdx.z];
  int v = blockIdx.x * 256 + threadIdx.x;
  int b = blockIdx.y;
  if (v >= J.N) return;
  const float* p = J.coords + ((size_t)b * J.N + v) * 3;
  int cx = cell1d(p[0], J.invh, J.G), cy = cell1d(p[1], J.invh, J.G), cz = cell1d(p[2], J.invh, J.G);
  atomicAdd(&J.cnt[b * J.ncells + (cz * J.G + cy) * J.G + cx], 1);
}

// ---------------- fused exclusive scan (one block per batch x job) ----------------
__global__ __launch_bounds__(1024) void scan_kernel(BinParams prm)
{
  const BinJob J = prm.job[blockIdx.y];
  const int b = blockIdx.x, t = threadIdx.x;
  const int ncells = J.ncells;
  const int* c  = J.cnt + (size_t)b * ncells;
  int* st = J.start + (size_t)b * (ncells + 1);
  int* cu = J.cur + (size_t)b * ncells;
  __shared__ int part[1024];
  const int chunk = (ncells + 1023) / 1024;
  const int lo = t * chunk, hi = min(lo + chunk, ncells);
  int s = 0;
  for (int i = lo; i < hi; ++i) s += c[i];
  part[t] = s;
  __syncthreads();
  for (int off = 1; off < 1024; off <<= 1) {
    int v = (t >= off) ? part[t - off] : 0;
    __syncthreads();
    part[t] += v;
    __syncthreads();
  }
  int base = (t > 0) ? part[t - 1] : 0;
  for (int i = lo; i < hi; ++i) { st[i] = base; cu[i] = base; base += c[i]; }
  if (t == 1023) st[ncells] = part[1023];
}

// ---------------- fused scatter: packed coords+idx into bin order ----------------
__global__ __launch_bounds__(256) void scatter_kernel(BinParams prm)
{
  const BinJob J = prm.job[blockIdx.z];
  int v = blockIdx.x * 256 + threadIdx.x;
  int b = blockIdx.y;
  if (v >= J.N) return;
  const float* p = J.coords + ((size_t)b * J.N + v) * 3;
  float x = p[0], y = p[1], z = p[2];
  int cx = cell1d(x, J.invh, J.G), cy = cell1d(y, J.invh, J.G), cz = cell1d(z, J.invh, J.G);
  int pos = atomicAdd(&J.cur[b * J.ncells + (cz * J.G + cy) * J.G + cx], 1);
  J.sorted[(size_t)b * J.N + pos] = make_float4(x, y, z, __int_as_float(v));
}

// ---------------- fused grid-pruned exact 3-NN query, 4 lanes per point, sorted points ----------------
__global__ __launch_bounds__(256) void query_kernel(
    const float4* __restrict__ psorted, Params prm)
{
  const int l = blockIdx.y, b = blockIdx.z;
  const Level L = prm.lv[l];
  const int tid = threadIdx.x;
  const int q = tid & 3;                        // quad lane
  const int sp = blockIdx.x * 64 + (tid >> 2);  // sorted point slot
  float4 pt = psorted[(size_t)b * NPOINTS + sp];
  const float px = pt.x, py = pt.y, pz = pt.z;
  const int p = __float_as_int(pt.w);           // original point id
  const int G = L.G;
  const float h = L.h;

  const int cx = cell1d(px, L.invh, G);
  const int cy = cell1d(py, L.invh, G);
  const int cz = cell1d(pz, L.invh, G);
  const float fx = px - cx * h, fy = py - cy * h, fz = pz - cz * h;
  float m = fminf(fminf(fminf(fx, h - fx), fminf(fy, h - fy)), fminf(fz, h - fz));
  m = fmaxf(m, 0.f);

  const int* start     = L.start  + (size_t)b * (L.ncells + 1);
  const float4* sorted = L.sorted + (size_t)b * L.Nv;

  float b0 = FLT_MAX, b1 = FLT_MAX, b2 = FLT_MAX;
  int   i0 = INT_MAX, i1 = INT_MAX, i2 = INT_MAX;

  auto ins = [&](float d2, int vi) {
    if (d2 < b2 || (d2 == b2 && vi < i2)) {
      if (d2 < b1 || (d2 == b1 && vi < i1)) {
        b2 = b1; i2 = i1;
        if (d2 < b0 || (d2 == b0 && vi < i0)) { b1 = b0; i1 = i0; b0 = d2; i0 = vi; }
        else                                  { b1 = d2; i1 = vi; }
      } else { b2 = d2; i2 = vi; }
    }
  };
  auto cand = [&](int k) {
    float4 vv = sorted[k];
    int vi = __float_as_int(vv.w);
    // exact reference arithmetic: individually-rounded squares, (x2+y2)+z2
    float dx = px - vv.x, dy = py - vv.y, dz = pz - vv.z;
    float d2 = __fadd_rn(__fadd_rn(__fmul_rn(dx, dx), __fmul_rn(dy, dy)),
                         __fmul_rn(dz, dz));
    ins(d2, vi);
  };
  auto scan_range = [&](int ks, int ke) {
    for (int k = ks + q; k < ke; k += 4) cand(k);
  };

  const int rmax = max(max(cx, G - 1 - cx), max(max(cy, G - 1 - cy), max(cz, G - 1 - cz)));
  for (int rho = 0; rho <= rmax; ++rho) {
    if (rho >= 1) {
      // quad-wide valid bound: union's true b2 <= min over lanes of local b2
      float bm = fminf(b2, __shfl_xor(b2, 1));
      bm = fminf(bm, __shfl_xor(bm, 2));
      float dmin = fmaxf((rho - 1) * h + m, 0.f);
      if (dmin * dmin * 0.99999f > bm) break;   // conservative exact-prune bound
    }
    const int z0 = max(cz - rho, 0), z1 = min(cz + rho, G - 1);
    const int y0 = max(cy - rho, 0), y1 = min(cy + rho, G - 1);
    for (int iz = z0; iz <= z1; ++iz) {
      const int adz = abs(iz - cz);
      for (int iy = y0; iy <= y1; ++iy) {
        const int ady = max(adz, abs(iy - cy));
        const int row = (iz * G + iy) * G;
        if (ady == rho) {
          const int x0 = max(cx - rho, 0), x1 = min(cx + rho, G - 1);
          scan_range(start[row + x0], start[row + x1 + 1]);
        } else {
          const int xl = cx - rho, xr = cx + rho;
          if (xl >= 0)     scan_range(start[row + xl], start[row + xl + 1]);
          if (xr <= G - 1) scan_range(start[row + xr], start[row + xr + 1]);
        }
      }
    }
  }

  // merge the 4 lanes' sorted triples (deterministic, lex (d2, idx))
  #pragma unroll
  for (int mask = 1; mask <= 2; mask <<= 1) {
    float c0 = __shfl_xor(b0, mask), c1 = __shfl_xor(b1, mask), c2 = __shfl_xor(b2, mask);
    int   j0 = __shfl_xor(i0, mask), j1 = __shfl_xor(i1, mask), j2 = __shfl_xor(i2, mask);
    ins(c0, j0); ins(c1, j1); ins(c2, j2);
  }

  if (q == 0) {
    float w0 = 1.0f / (sqrtf(b0) + 1e-8f);
    float w1 = 1.0f / (sqrtf(b1) + 1e-8f);
    float w2 = 1.0f / (sqrtf(b2) + 1e-8f);
    float ws = (w0 + w1) + w2;
    size_t o = ((size_t)b * NPOINTS + p) * 3;
    L.idxo[o] = i0; L.idxo[o + 1] = i1; L.idxo[o + 2] = i2;
    L.wo[o] = w0 / ws; L.wo[o + 1] = w1 / ws; L.wo[o + 2] = w2 / ws;
  }
}

// ---------------- Gather-interp (float4) + per-block channel partial sums ----------------
template <int C, int BDIM>
__global__ __launch_bounds__(BDIM) void interp_kernel(
    const float* __restrict__ voxf, const int* __restrict__ idxo,
    const float* __restrict__ wo, float* __restrict__ out,
    float* __restrict__ psum, float* __restrict__ psq, int Nv)
{
  constexpr int C4 = C / 4;
  constexpr int R  = BDIM / C4;
  const int b = blockIdx.y, blk = blockIdx.x;
  const int tid = threadIdx.x;
  const int r = tid / C4, c4 = tid - r * C4;
  const float4* fb = (const float4*)(voxf + (size_t)b * Nv * C);
  float4* ob = (float4*)(out + (size_t)b * NPOINTS * C);
  const int p0 = blk * NPB;

  float4 s = make_float4(0, 0, 0, 0), q = make_float4(0, 0, 0, 0);
  for (int p = p0 + r; p < p0 + NPB; p += R) {
    size_t pg = ((size_t)b * NPOINTS + p) * 3;
    int   ia = idxo[pg], ib = idxo[pg + 1], ic = idxo[pg + 2];
    float wa = wo[pg],   wb = wo[pg + 1],   wc = wo[pg + 2];
    float4 fa = fb[(size_t)ia * C4 + c4];
    float4 f2 = fb[(size_t)ib * C4 + c4];
    float4 fc = fb[(size_t)ic * C4 + c4];
    float4 o;
    o.x = wa * fa.x + wb * f2.x + wc * fc.x;
    o.y = wa * fa.y + wb * f2.y + wc * fc.y;
    o.z = wa * fa.z + wb * f2.z + wc * fc.z;
    o.w = wa * fa.w + wb * f2.w + wc * fc.w;
    ob[(size_t)p * C4 + c4] = o;
    s.x += o.x; s.y += o.y; s.z += o.z; s.w += o.w;
    q.x += o.x * o.x; q.y += o.y * o.y; q.z += o.z * o.z; q.w += o.w * o.w;
  }

  __shared__ float4 ls[BDIM];
  ls[tid] = s;
  __syncthreads();
  if (r == 0) {
    float4 tot = s;
    #pragma unroll
    for (int rr = 1; rr < R; ++rr) {
      float4 v = ls[c4 + rr * C4];
      tot.x += v.x; tot.y += v.y; tot.z += v.z; tot.w += v.w;
    }
    ((float4*)psum)[((size_t)b * NBLK + blk) * C4 + c4] = tot;
  }
  __syncthreads();
  ls[tid] = q;
  __syncthreads();
  if (r == 0) {
    float4 tot = q;
    #pragma unroll
    for (int rr = 1; rr < R; ++rr) {
      float4 v = ls[c4 + rr * C4];
      tot.x += v.x; tot.y += v.y; tot.z += v.z; tot.w += v.w;
    }
    ((float4*)psq)[((size_t)b * NBLK + blk) * C4 + c4] = tot;
  }
}

// ---------------- BN stats (parallel reduce over NBLK partials) ----------------
__global__ __launch_bounds__(256) void bn_stats_kernel(
    const float* __restrict__ psum, const float* __restrict__ psq,
    const float* __restrict__ gamma, const float* __restrict__ beta,
    float* __restrict__ scale, float* __restrict__ shift, int C, float invN)
{
  const int c = blockIdx.x, b = blockIdx.y, t = threadIdx.x;
  float s = 0.f, q = 0.f;
  for (int k = t; k < NBLK; k += 256) {
    s += psum[((size_t)b * NBLK + k) * C + c];
    q += psq[((size_t)b * NBLK + k) * C + c];
  }
  __shared__ float ss[256], qs[256];
  ss[t] = s; qs[t] = q;
  __syncthreads();
  for (int o = 128; o > 0; o >>= 1) {
    if (t < o) { ss[t] += ss[t + o]; qs[t] += qs[t + o]; }
    __syncthreads();
  }
  if (t == 0) {
    float mu  = ss[0] * invN;
    float var = fmaxf(qs[0] * invN - mu * mu, 0.f);
    float sc  = gamma[c] * rsqrtf(var + 1e-5f);
    scale[b * C + c] = sc;
    shift[b * C + c] = beta[c] - mu * sc;
  }
}

// ---------------- In-place normalize (float4) ----------------
__global__ __launch_bounds__(256) void bn_apply_kernel(
    float* __restrict__ out, const float* __restrict__ scale,
    const float* __restrict__ shift, int C, int NpC)
{
  const int e = blockIdx.x * 256 + threadIdx.x;
  const int npc4 = NpC >> 2, c4n = C >> 2;
  const int b = e / npc4;
  const int rem = e - b * npc4;
  const int c4 = rem % c4n;
  float4 v  = ((float4*)out)[e];
  float4 sc = ((const float4*)scale)[b * c4n + c4];
  float4 sh = ((const float4*)shift)[b * c4n + c4];
  v.x = fmaf(v.x, sc.x, sh.x);
  v.y = fmaf(v.y, sc.y, sh.y);
  v.z = fmaf(v.z, sc.z, sh.z);
  v.w = fmaf(v.w, sc.w, sh.w);
  ((float4*)out)[e] = v;
}

// ---------------- Host launch ----------------
extern "C" void kernel_launch(void* const* d_in, const int* in_sizes, int n_in,
                              void* d_out, int out_size, void* d_ws, size_t ws_size,
                              hipStream_t stream)
{
  const float* ptc = (const float*)d_in[0];
  static const int    Cs[4]     = {256, 128, 96, 96};
  static const int    Nvs[4]    = {2048, 6144, 16384, 32768};
  static const int    Gs[4]     = {10, 14, 18, 22};
  static const size_t outOff[4] = {0, 16777216, 25165824, 31457280};

  // ---- workspace carve ----
  size_t off = 0;
  auto carve = [&](size_t bytes) {
    off = (off + 255) & ~(size_t)255;
    size_t o = off; off += bytes; return o;
  };
  char* w = (char*)d_ws;

  int nc[NJOB];
  for (int l = 0; l < 4; ++l) nc[l] = Gs[l] * Gs[l] * Gs[l];
  nc[4] = PCELLS;
  int Ns[NJOB] = {Nvs[0], Nvs[1], Nvs[2], Nvs[3], NPOINTS};
  int Gj[NJOB] = {Gs[0], Gs[1], Gs[2], Gs[3], PG};

  // contiguous counter block (zeroed with one launch)
  int totcnt = 0;
  for (int j = 0; j < NJOB; ++j) totcnt += nc[j];
  int* cntbase = (int*)(w + carve((size_t)NBATCH * totcnt * 4));

  float4* sortedj[NJOB]; int* cntj[NJOB]; int* sttj[NJOB]; int* curj[NJOB];
  {
    int acc = 0;
    for (int j = 0; j < NJOB; ++j) {
      cntj[j] = cntbase + (size_t)NBATCH * acc;
      acc += nc[j];
    }
  }
  for (int j = 0; j < NJOB; ++j) {
    sortedj[j] = (float4*)(w + carve((size_t)NBATCH * Ns[j] * 16));
    sttj[j]    = (int*)   (w + carve((size_t)NBATCH * (nc[j] + 1) * 4));
    curj[j]    = (int*)   (w + carve((size_t)NBATCH * nc[j] * 4));
  }
  int*   idxo  = (int*)  (w + carve((size_t)NLEV * NBATCH * NPOINTS * 3 * 4));
  float* wo    = (float*)(w + carve((size_t)NLEV * NBATCH * NPOINTS * 3 * 4));
  float* psum  = (float*)(w + carve((size_t)NBATCH * NBLK * 256 * 4));
  float* psq   = (float*)(w + carve((size_t)NBATCH * NBLK * 256 * 4));
  float* scale = (float*)(w + carve((size_t)NBATCH * 256 * 4));
  float* shift = (float*)(w + carve((size_t)NBATCH * 256 * 4));

  BinParams bp;
  for (int j = 0; j < NJOB; ++j) {
    BinJob& J = bp.job[j];
    J.coords = (j < 4) ? (const float*)d_in[1 + 4 * j] : ptc;
    J.cnt = cntj[j]; J.start = sttj[j]; J.cur = curj[j]; J.sorted = sortedj[j];
    J.G = Gj[j]; J.ncells = nc[j]; J.N = Ns[j];
    J.invh = Gj[j] / 50.0f;
  }

  Params prm;
  for (int l = 0; l < 4; ++l) {
    Level& L = prm.lv[l];
    L.sorted = sortedj[l]; L.start = sttj[l];
    L.idxo = idxo + (size_t)l * NBATCH * NPOINTS * 3;
    L.wo   = wo   + (size_t)l * NBATCH * NPOINTS * 3;
    L.G = Gs[l]; L.ncells = nc[l]; L.Nv = Nvs[l];
    L.h = 50.0f / Gs[l]; L.invh = Gs[l] / 50.0f;
  }

  // ---- fused binning: zero, count, scan, scatter (all 5 jobs) ----
  const int zn = NBATCH * totcnt;
  zero_kernel<<<(zn + 255) / 256, 256, 0, stream>>>(cntbase, zn);
  count_kernel<<<dim3((NPOINTS + 255) / 256, NBATCH, NJOB), 256, 0, stream>>>(bp);
  scan_kernel<<<dim3(NBATCH, NJOB), 1024, 0, stream>>>(bp);
  scatter_kernel<<<dim3((NPOINTS + 255) / 256, NBATCH, NJOB), 256, 0, stream>>>(bp);

  // ---- fused exact 3-NN query over all levels (4 lanes per point, sorted order) ----
  query_kernel<<<dim3(NPOINTS / 64, NLEV, NBATCH), 256, 0, stream>>>(sortedj[4], prm);

  // ---- per-level interp + BN ----
  for (int l = 0; l < 4; ++l) {
    const float* voxf  = (const float*)d_in[2 + 4 * l];
    const float* gamma = (const float*)d_in[3 + 4 * l];
    const float* beta  = (const float*)d_in[4 + 4 * l];
    const int C = Cs[l], Nv = Nvs[l];
    float* outl = (float*)d_out + outOff[l];
    const int* idl = idxo + (size_t)l * NBATCH * NPOINTS * 3;
    const float* wl = wo  + (size_t)l * NBATCH * NPOINTS * 3;

    if (C == 256)
      interp_kernel<256, 256><<<dim3(NBLK, NBATCH), 256, 0, stream>>>(
          voxf, idl, wl, outl, psum, psq, Nv);
    else if (C == 128)
      interp_kernel<128, 256><<<dim3(NBLK, NBATCH), 256, 0, stream>>>(
          voxf, idl, wl, outl, psum, psq, Nv);
    else
      interp_kernel<96, 240><<<dim3(NBLK, NBATCH), 240, 0, stream>>>(
          voxf, idl, wl, outl, psum, psq, Nv);

    bn_stats_kernel<<<dim3(C, NBATCH), 256, 0, stream>>>(
        psum, psq, gamma, beta, scale, shift, C, 1.0f / NPOINTS);

    const int n4 = NBATCH * NPOINTS * C / 4;
    bn_apply_kernel<<<n4 / 256, 256, 0, stream>>>(
        (float*)outl, scale, shift, C, NPOINTS * C);
  }
}